// Round 1
// baseline (465.554 us; speedup 1.0000x reference)
//
#include <hip/hip_runtime.h>

// GNNDecoder: out = relu((einsum("nk,nkl->nl", s, z[batch])) @ W1 + b1) @ W2 + b2
// N=100000, B=256, K=32, LATENT=64, HIDDEN=256, OUT=32. All fp32; batch int32.

constexpr int NN     = 100000;
constexpr int KK     = 32;
constexpr int LATENT = 64;
constexpr int HIDDEN = 256;
constexpr int OUTD   = 32;

constexpr int NODES_PER_BLOCK = 64;
constexpr int BLOCK = 256;

__global__ __launch_bounds__(BLOCK, 3)
void gnn_decoder(const float* __restrict__ z,      // [B, K, LATENT]
                 const float* __restrict__ s,      // [N, K]
                 const int*   __restrict__ batch,  // [N]
                 const float* __restrict__ W1,     // [LATENT, HIDDEN]
                 const float* __restrict__ b1,     // [HIDDEN]
                 const float* __restrict__ W2,     // [HIDDEN, OUT]
                 const float* __restrict__ b2,     // [OUT]
                 float*       __restrict__ out)    // [N, OUT]
{
    // LDS union: phase0/A uses s_tile + lat + bidx; phase B reuses as partial.
    __shared__ union SM {
        struct {
            float s_tile[NODES_PER_BLOCK][KK + 1];        // +1 pad: (n+k)%32 banks
            float lat[NODES_PER_BLOCK][LATENT + 1];       // +1 pad: (i+l)%32 banks
            int   bidx[NODES_PER_BLOCK];
        } p0;
        float partial[4][NODES_PER_BLOCK][OUTD + 1];      // +1 pad
    } sm;

    const int t = threadIdx.x;
    const int block_n0 = blockIdx.x * NODES_PER_BLOCK;

    // ---------------- phase 0a: stage s tile + batch indices ----------------
    {
        const float* s_src = s + (size_t)block_n0 * KK;
        #pragma unroll
        for (int idx = t; idx < NODES_PER_BLOCK * KK; idx += BLOCK) {
            const int n = idx / KK, k = idx % KK;
            const int gn = block_n0 + n;
            sm.p0.s_tile[n][k] = (gn < NN) ? s_src[idx] : 0.f;
        }
        if (t < NODES_PER_BLOCK) {
            const int gn = block_n0 + t;
            sm.p0.bidx[t] = (gn < NN) ? batch[gn] : 0;
        }
    }
    __syncthreads();

    // ---------------- phase 0b: lat[n][l] = sum_k s[n][k] * z[b][k][l] -------
    {
        const int n  = t >> 2;        // node within block (0..63)
        const int lc = t & 3;         // latent chunk (16 latents each)
        const int l0 = lc * 16;
        const int b  = sm.p0.bidx[n];
        const float* zb = z + (size_t)b * KK * LATENT + l0;

        float acc[16];
        #pragma unroll
        for (int i = 0; i < 16; ++i) acc[i] = 0.f;

        #pragma unroll 4
        for (int k = 0; k < KK; ++k) {
            const float sk = sm.p0.s_tile[n][k];
            const float4* zp = (const float4*)(zb + k * LATENT);
            const float4 z0 = zp[0], z1 = zp[1], z2 = zp[2], z3 = zp[3];
            acc[0]  += sk * z0.x;  acc[1]  += sk * z0.y;
            acc[2]  += sk * z0.z;  acc[3]  += sk * z0.w;
            acc[4]  += sk * z1.x;  acc[5]  += sk * z1.y;
            acc[6]  += sk * z1.z;  acc[7]  += sk * z1.w;
            acc[8]  += sk * z2.x;  acc[9]  += sk * z2.y;
            acc[10] += sk * z2.z;  acc[11] += sk * z2.w;
            acc[12] += sk * z3.x;  acc[13] += sk * z3.y;
            acc[14] += sk * z3.z;  acc[15] += sk * z3.w;
        }
        #pragma unroll
        for (int i = 0; i < 16; ++i) sm.p0.lat[n][l0 + i] = acc[i];
    }
    __syncthreads();

    // ---------------- stage A: h[j*64+hh] = sum_l lat[i][l] * W1[l][hh] ------
    const int i = t & 63;   // node
    const int j = t >> 6;   // hidden chunk (64 hiddens each)

    float h[64];
    #pragma unroll
    for (int x = 0; x < 64; ++x) h[x] = 0.f;

    const float* W1j = W1 + j * 64;
    #pragma unroll 2
    for (int l = 0; l < LATENT; ++l) {
        const float lv = sm.p0.lat[i][l];
        const float4* wp = (const float4*)(W1j + (size_t)l * HIDDEN);
        #pragma unroll
        for (int q = 0; q < 16; ++q) {
            const float4 w = wp[q];
            h[q * 4 + 0] += lv * w.x;
            h[q * 4 + 1] += lv * w.y;
            h[q * 4 + 2] += lv * w.z;
            h[q * 4 + 3] += lv * w.w;
        }
    }

    // ---------------- stage B: op[o] += relu(h+b1) * W2[hh][o] ---------------
    float op[32];
    #pragma unroll
    for (int o = 0; o < 32; ++o) op[o] = 0.f;

    const float* b1j = b1 + j * 64;
    #pragma unroll 2
    for (int hh = 0; hh < 64; ++hh) {
        float r = h[hh] + b1j[hh];
        r = r > 0.f ? r : 0.f;
        const float4* w2p = (const float4*)(W2 + (size_t)(j * 64 + hh) * OUTD);
        #pragma unroll
        for (int q = 0; q < 8; ++q) {
            const float4 w = w2p[q];
            op[q * 4 + 0] += r * w.x;
            op[q * 4 + 1] += r * w.y;
            op[q * 4 + 2] += r * w.z;
            op[q * 4 + 3] += r * w.w;
        }
    }

    __syncthreads();   // lat tile dead; safe to overlay partial

    #pragma unroll
    for (int o = 0; o < 32; ++o) sm.partial[j][i][o] = op[o];
    __syncthreads();

    // ---------------- reduce over 4 hidden chunks + bias + store -------------
    {
        const int n  = t >> 2;
        const int o0 = (t & 3) * 8;
        const int gn = block_n0 + n;
        if (gn < NN) {
            float* dst = out + (size_t)gn * OUTD + o0;
            #pragma unroll
            for (int q = 0; q < 8; ++q) {
                const float v = sm.partial[0][n][o0 + q]
                              + sm.partial[1][n][o0 + q]
                              + sm.partial[2][n][o0 + q]
                              + sm.partial[3][n][o0 + q]
                              + b2[o0 + q];
                dst[q] = v;
            }
        }
    }
}

extern "C" void kernel_launch(void* const* d_in, const int* in_sizes, int n_in,
                              void* d_out, int out_size, void* d_ws, size_t ws_size,
                              hipStream_t stream) {
    const float* z     = (const float*)d_in[0];
    const float* s     = (const float*)d_in[1];
    const int*   batch = (const int*)d_in[2];
    const float* W1    = (const float*)d_in[3];
    const float* b1    = (const float*)d_in[4];
    const float* W2    = (const float*)d_in[5];
    const float* b2    = (const float*)d_in[6];
    float* out = (float*)d_out;

    const int grid = (NN + NODES_PER_BLOCK - 1) / NODES_PER_BLOCK;  // 1563
    gnn_decoder<<<grid, BLOCK, 0, stream>>>(z, s, batch, W1, b1, W2, b2, out);
}

// Round 2
// 457.927 us; speedup vs baseline: 1.0167x; 1.0167x over previous
//
#include <hip/hip_runtime.h>

// GNNDecoder: out = relu((einsum("nk,nkl->nl", s, z[batch])) @ W1 + b1) @ W2 + b2
// N=100000, B=256, K=32, LATENT=64, HIDDEN=256, OUT=32. All fp32; batch int32.
//
// R1 lesson: dynamic index h[hh] sank the accumulator array to scratch
// (VGPR=72 < 96 accumulators declared) -> 465us latency-bound. This version
// chunks HIDDEN into 16-wide groups with fully-unrolled static indexing so
// everything lives in VGPRs, and coalesces the output stores (float4/lane).

constexpr int NN     = 100000;
constexpr int KK     = 32;
constexpr int LATENT = 64;
constexpr int HIDDEN = 256;
constexpr int OUTD   = 32;

constexpr int NODES_PER_BLOCK = 64;
constexpr int BLOCK = 256;

__global__ __launch_bounds__(BLOCK, 4)
void gnn_decoder(const float* __restrict__ z,      // [B, K, LATENT]
                 const float* __restrict__ s,      // [N, K]
                 const int*   __restrict__ batch,  // [N]
                 const float* __restrict__ W1,     // [LATENT, HIDDEN]
                 const float* __restrict__ b1,     // [HIDDEN]
                 const float* __restrict__ W2,     // [HIDDEN, OUT]
                 const float* __restrict__ b2,     // [OUT]
                 float*       __restrict__ out)    // [N, OUT]
{
    __shared__ union SM {
        struct {
            float s_tile[NODES_PER_BLOCK][KK + 1];   // +1 pad: (n+k)%32 banks
            float lat[NODES_PER_BLOCK][LATENT + 1];  // +1 pad: (i+l)%32 banks
            int   bidx[NODES_PER_BLOCK];
        } p0;
        float partial[4][NODES_PER_BLOCK][OUTD + 1]; // row stride 33: <=2-way
    } sm;

    const int t = threadIdx.x;
    const int block_n0 = blockIdx.x * NODES_PER_BLOCK;

    // ---------------- phase 0a: stage s tile + batch indices ----------------
    {
        const float* s_src = s + (size_t)block_n0 * KK;
        #pragma unroll
        for (int idx = t; idx < NODES_PER_BLOCK * KK; idx += BLOCK) {
            const int n = idx >> 5, k = idx & 31;
            const int gn = block_n0 + n;
            sm.p0.s_tile[n][k] = (gn < NN) ? s_src[idx] : 0.f;
        }
        if (t < NODES_PER_BLOCK) {
            const int gn = block_n0 + t;
            sm.p0.bidx[t] = (gn < NN) ? batch[gn] : 0;
        }
    }
    __syncthreads();

    // ---------------- phase 0b: lat[n][l] = sum_k s[n][k] * z[b][k][l] -------
    {
        const int n  = t >> 2;        // node within block (0..63)
        const int lc = t & 3;         // latent chunk (16 latents each)
        const int l0 = lc * 16;
        const int b  = sm.p0.bidx[n];
        const float* zb = z + (size_t)b * KK * LATENT + l0;

        float acc[16];
        #pragma unroll
        for (int i = 0; i < 16; ++i) acc[i] = 0.f;

        #pragma unroll 4
        for (int k = 0; k < KK; ++k) {
            const float sk = sm.p0.s_tile[n][k];
            const float4* zp = (const float4*)(zb + k * LATENT);
            const float4 z0 = zp[0], z1 = zp[1], z2 = zp[2], z3 = zp[3];
            acc[0]  += sk * z0.x;  acc[1]  += sk * z0.y;
            acc[2]  += sk * z0.z;  acc[3]  += sk * z0.w;
            acc[4]  += sk * z1.x;  acc[5]  += sk * z1.y;
            acc[6]  += sk * z1.z;  acc[7]  += sk * z1.w;
            acc[8]  += sk * z2.x;  acc[9]  += sk * z2.y;
            acc[10] += sk * z2.z;  acc[11] += sk * z2.w;
            acc[12] += sk * z3.x;  acc[13] += sk * z3.y;
            acc[14] += sk * z3.z;  acc[15] += sk * z3.w;
        }
        #pragma unroll
        for (int i = 0; i < 16; ++i) sm.p0.lat[n][l0 + i] = acc[i];
    }
    __syncthreads();

    // ------- stages A+B fused, chunked 16-wide so ALL indices are static -----
    const int i = t & 63;   // node
    const int j = t >> 6;   // hidden chunk of 64 (wave-uniform)

    float op[32];
    #pragma unroll
    for (int o = 0; o < 32; ++o) op[o] = 0.f;

    #pragma unroll 1
    for (int c = 0; c < 4; ++c) {                 // 4 chunks x 16 hidden
        const int h0 = j * 64 + c * 16;

        float h[16];
        #pragma unroll
        for (int x = 0; x < 16; ++x) h[x] = 0.f;

        const float* W1p = W1 + h0;
        #pragma unroll 4
        for (int l = 0; l < LATENT; ++l) {
            const float lv = sm.p0.lat[i][l];     // per-lane distinct i: 2-way max
            const float4* wp = (const float4*)(W1p + (size_t)l * HIDDEN);
            const float4 w0 = wp[0], w1 = wp[1], w2 = wp[2], w3 = wp[3];
            h[0]  += lv * w0.x;  h[1]  += lv * w0.y;
            h[2]  += lv * w0.z;  h[3]  += lv * w0.w;
            h[4]  += lv * w1.x;  h[5]  += lv * w1.y;
            h[6]  += lv * w1.z;  h[7]  += lv * w1.w;
            h[8]  += lv * w2.x;  h[9]  += lv * w2.y;
            h[10] += lv * w2.z;  h[11] += lv * w2.w;
            h[12] += lv * w3.x;  h[13] += lv * w3.y;
            h[14] += lv * w3.z;  h[15] += lv * w3.w;
        }

        #pragma unroll
        for (int hh = 0; hh < 16; ++hh) {         // FULLY unrolled: static h[hh]
            float r = h[hh] + b1[h0 + hh];
            r = r > 0.f ? r : 0.f;
            const float4* w2p = (const float4*)(W2 + (size_t)(h0 + hh) * OUTD);
            #pragma unroll
            for (int q = 0; q < 8; ++q) {
                const float4 w = w2p[q];
                op[q * 4 + 0] += r * w.x;
                op[q * 4 + 1] += r * w.y;
                op[q * 4 + 2] += r * w.z;
                op[q * 4 + 3] += r * w.w;
            }
        }
    }

    __syncthreads();   // p0 dead; safe to overlay partial

    #pragma unroll
    for (int o = 0; o < 32; ++o) sm.partial[j][i][o] = op[o];
    __syncthreads();

    // ------- reduce over 4 hidden chunks + bias + coalesced float4 store -----
    {
        const int o0 = (t & 7) * 4;               // float4 slot within row
        #pragma unroll
        for (int rep = 0; rep < 2; ++rep) {
            const int n  = rep * 32 + (t >> 3);   // 8 lanes per node
            const int gn = block_n0 + n;
            if (gn < NN) {
                float4 v;
                v.x = sm.partial[0][n][o0 + 0] + sm.partial[1][n][o0 + 0]
                    + sm.partial[2][n][o0 + 0] + sm.partial[3][n][o0 + 0] + b2[o0 + 0];
                v.y = sm.partial[0][n][o0 + 1] + sm.partial[1][n][o0 + 1]
                    + sm.partial[2][n][o0 + 1] + sm.partial[3][n][o0 + 1] + b2[o0 + 1];
                v.z = sm.partial[0][n][o0 + 2] + sm.partial[1][n][o0 + 2]
                    + sm.partial[2][n][o0 + 2] + sm.partial[3][n][o0 + 2] + b2[o0 + 2];
                v.w = sm.partial[0][n][o0 + 3] + sm.partial[1][n][o0 + 3]
                    + sm.partial[2][n][o0 + 3] + sm.partial[3][n][o0 + 3] + b2[o0 + 3];
                *(float4*)(out + (size_t)gn * OUTD + o0) = v;  // lane-consecutive
            }
        }
    }
}

extern "C" void kernel_launch(void* const* d_in, const int* in_sizes, int n_in,
                              void* d_out, int out_size, void* d_ws, size_t ws_size,
                              hipStream_t stream) {
    const float* z     = (const float*)d_in[0];
    const float* s     = (const float*)d_in[1];
    const int*   batch = (const int*)d_in[2];
    const float* W1    = (const float*)d_in[3];
    const float* b1    = (const float*)d_in[4];
    const float* W2    = (const float*)d_in[5];
    const float* b2    = (const float*)d_in[6];
    float* out = (float*)d_out;

    const int grid = (NN + NODES_PER_BLOCK - 1) / NODES_PER_BLOCK;  // 1563
    gnn_decoder<<<grid, BLOCK, 0, stream>>>(z, s, batch, W1, b1, W2, b2, out);
}

// Round 3
// 184.498 us; speedup vs baseline: 2.5234x; 2.4820x over previous
//
#include <hip/hip_runtime.h>

// GNNDecoder: out = relu((einsum("nk,nkl->nl", s, z[batch])) @ W1 + b1) @ W2 + b2
// N=100000, B=256, K=32, LATENT=64, HIDDEN=256, OUT=32. All fp32; batch int32.
//
// R1/R2 lesson: holding h[16]+op[32]+16 W1 float4 live crosses the VGPR cap;
// the allocator spills h[] to scratch (WRITE_SIZE 102MB = 400k thr * 64 * 4B,
// VALUBusy 10%, latency-bound). R3: split OUT across waves (op[8]/thread) and
// pass relu(h) through LDS in 64-hidden chunks -> peak live set ~50 VGPR.
// All LDS arrays transposed [feature][node]: every access is (const+lane)%32
// -> <=2-way bank aliasing (free on gfx950, m136). Weights read via
// readfirstlane-forced scalar loads (wave-uniform broadcast).

constexpr int NN     = 100000;
constexpr int KK     = 32;
constexpr int LATENT = 64;
constexpr int HIDDEN = 256;
constexpr int OUTD   = 32;

constexpr int NODES_PER_BLOCK = 64;
constexpr int BLOCK = 256;

__global__ __launch_bounds__(BLOCK, 4)
void gnn_decoder(const float* __restrict__ z,      // [B, K, LATENT]
                 const float* __restrict__ s,      // [N, K]
                 const int*   __restrict__ batch,  // [N]
                 const float* __restrict__ W1,     // [LATENT, HIDDEN]
                 const float* __restrict__ b1,     // [HIDDEN]
                 const float* __restrict__ W2,     // [HIDDEN, OUT]
                 const float* __restrict__ b2,     // [OUT]
                 float*       __restrict__ out)    // [N, OUT]
{
    // lat_t[l][n]: node latents, transposed. Stays live through all chunks.
    __shared__ float lat_t[LATENT][NODES_PER_BLOCK + 1];
    // hc overlays s_tile/bidx (dead after phase 0b; barrier in between).
    __shared__ union HcU {
        struct P0 {
            float s_tile[NODES_PER_BLOCK][KK + 1];
            int   bidx[NODES_PER_BLOCK];
        } p0;
        float hc[64][NODES_PER_BLOCK + 1];   // hc[hh_local][n] = relu(h)+..
    } u;

    const int t = threadIdx.x;
    const int block_n0 = blockIdx.x * NODES_PER_BLOCK;

    // ---------------- phase 0a: stage s tile + batch indices ----------------
    {
        const float* s_src = s + (size_t)block_n0 * KK;
        #pragma unroll
        for (int idx = t; idx < NODES_PER_BLOCK * KK; idx += BLOCK) {
            const int n = idx >> 5, k = idx & 31;
            const int gn = block_n0 + n;
            u.p0.s_tile[n][k] = (gn < NN) ? s_src[idx] : 0.f;
        }
        if (t < NODES_PER_BLOCK) {
            const int gn = block_n0 + t;
            u.p0.bidx[t] = (gn < NN) ? batch[gn] : 0;
        }
    }
    __syncthreads();

    // -------- phase 0b: lat_t[l][n] = sum_k s[n][k] * z[b][k][l] ------------
    {
        const int n  = t >> 2;        // node (0..63)
        const int lc = t & 3;         // latent chunk of 16
        const int l0 = lc * 16;
        const int b  = u.p0.bidx[n];
        const float* zb = z + (size_t)b * KK * LATENT + l0;

        float acc[16];
        #pragma unroll
        for (int x = 0; x < 16; ++x) acc[x] = 0.f;

        #pragma unroll 4
        for (int k = 0; k < KK; ++k) {
            const float sk = u.p0.s_tile[n][k];
            const float4* zp = (const float4*)(zb + k * LATENT);
            const float4 z0 = zp[0], z1 = zp[1], z2 = zp[2], z3 = zp[3];
            acc[0]  += sk * z0.x;  acc[1]  += sk * z0.y;
            acc[2]  += sk * z0.z;  acc[3]  += sk * z0.w;
            acc[4]  += sk * z1.x;  acc[5]  += sk * z1.y;
            acc[6]  += sk * z1.z;  acc[7]  += sk * z1.w;
            acc[8]  += sk * z2.x;  acc[9]  += sk * z2.y;
            acc[10] += sk * z2.z;  acc[11] += sk * z2.w;
            acc[12] += sk * z3.x;  acc[13] += sk * z3.y;
            acc[14] += sk * z3.z;  acc[15] += sk * z3.w;
        }
        // write transposed: bank (16*lc + q + n) % 32 -> 2-way, free
        #pragma unroll
        for (int q = 0; q < 16; ++q) lat_t[l0 + q][n] = acc[q];
    }
    __syncthreads();   // lat ready; s_tile dead -> hc overlay is safe

    const int i   = t & 63;                                   // node lane
    const int sub = __builtin_amdgcn_readfirstlane(t >> 6);   // wave id 0..3

    float op[8];
    #pragma unroll
    for (int o = 0; o < 8; ++o) op[o] = 0.f;

    #pragma unroll 1
    for (int c = 0; c < 4; ++c) {     // 4 chunks of 64 hidden
        // ---- stage A: h[q] for hiddens hg = c*64 + sub*16 + q -------------
        float h[16];
        #pragma unroll
        for (int x = 0; x < 16; ++x) h[x] = 0.f;

        const float* W1p = W1 + c * 64 + sub * 16;   // scalar base (sub uniform)
        #pragma unroll 4
        for (int l = 0; l < LATENT; ++l) {
            const float lv = lat_t[l][i];            // b32, (l+i)%32 2-way
            const float4* wp = (const float4*)(W1p + (size_t)l * HIDDEN);
            const float4 w0 = wp[0], w1 = wp[1], w2 = wp[2], w3 = wp[3];
            h[0]  += lv * w0.x;  h[1]  += lv * w0.y;
            h[2]  += lv * w0.z;  h[3]  += lv * w0.w;
            h[4]  += lv * w1.x;  h[5]  += lv * w1.y;
            h[6]  += lv * w1.z;  h[7]  += lv * w1.w;
            h[8]  += lv * w2.x;  h[9]  += lv * w2.y;
            h[10] += lv * w2.z;  h[11] += lv * w2.w;
            h[12] += lv * w3.x;  h[13] += lv * w3.y;
            h[14] += lv * w3.z;  h[15] += lv * w3.w;
        }

        // relu + b1 -> hc transposed (bank (const+i)%32, 2-way free)
        #pragma unroll
        for (int q = 0; q < 16; ++q) {
            float r = h[q] + b1[c * 64 + sub * 16 + q];
            r = r > 0.f ? r : 0.f;
            u.hc[sub * 16 + q][i] = r;
        }
        __syncthreads();

        // ---- stage B: op[0..7] += hc[hh][i] * W2[c*64+hh][sub*8 + ..] -----
        const float* W2p = W2 + (size_t)c * 64 * OUTD + sub * 8;
        #pragma unroll 4
        for (int hh = 0; hh < 64; ++hh) {
            const float r = u.hc[hh][i];             // b32, (hh+i)%32 2-way
            const float4* wp = (const float4*)(W2p + (size_t)hh * OUTD);
            const float4 w0 = wp[0], w1 = wp[1];
            op[0] += r * w0.x;  op[1] += r * w0.y;
            op[2] += r * w0.z;  op[3] += r * w0.w;
            op[4] += r * w1.x;  op[5] += r * w1.y;
            op[6] += r * w1.z;  op[7] += r * w1.w;
        }
        if (c < 3) __syncthreads();   // before next chunk overwrites hc
    }

    // ---- store: 32B contiguous per lane, sector-aligned, no reduction -----
    {
        const int gn = block_n0 + i;
        if (gn < NN) {
            const float* b2p = b2 + sub * 8;
            float4 v0, v1;
            v0.x = op[0] + b2p[0];  v0.y = op[1] + b2p[1];
            v0.z = op[2] + b2p[2];  v0.w = op[3] + b2p[3];
            v1.x = op[4] + b2p[4];  v1.y = op[5] + b2p[5];
            v1.z = op[6] + b2p[6];  v1.w = op[7] + b2p[7];
            float* dst = out + (size_t)gn * OUTD + sub * 8;
            *(float4*)dst       = v0;
            *((float4*)dst + 1) = v1;
        }
    }
}

extern "C" void kernel_launch(void* const* d_in, const int* in_sizes, int n_in,
                              void* d_out, int out_size, void* d_ws, size_t ws_size,
                              hipStream_t stream) {
    const float* z     = (const float*)d_in[0];
    const float* s     = (const float*)d_in[1];
    const int*   batch = (const int*)d_in[2];
    const float* W1    = (const float*)d_in[3];
    const float* b1    = (const float*)d_in[4];
    const float* W2    = (const float*)d_in[5];
    const float* b2    = (const float*)d_in[6];
    float* out = (float*)d_out;

    const int grid = (NN + NODES_PER_BLOCK - 1) / NODES_PER_BLOCK;  // 1563
    gnn_decoder<<<grid, BLOCK, 0, stream>>>(z, s, batch, W1, b1, W2, b2, out);
}

// Round 4
// 138.065 us; speedup vs baseline: 3.3720x; 1.3363x over previous
//
#include <hip/hip_runtime.h>

// GNNDecoder: out = relu((einsum("nk,nkl->nl", s, z[batch])) @ W1 + b1) @ W2 + b2
// N=100000, B=256, K=32, LATENT=64, HIDDEN=256, OUT=32. fp32 in/out.
//
// R3 post-mortem: fp32 path is 69% stalled (VALUBusy 31%), and even perfect
// issue caps at the 34us vector-FMA floor. R4: stages A/B on f16 MFMA
// (16x16x32_f16). Weights are pre-converted+pre-swizzled into B-fragment
// order in d_ws by a tiny first kernel, so each B-frag is ONE coalesced
// global_load_dwordx4. lat and relu(h) pass through LDS as f16 in
// A-fragment row-major layout (+8 f16 pad -> <=2-way banks, free).
// Verified layouts (learn_hip m89/m120): A[m=lane&15][k=quad*8+j],
// B[k=quad*8+j][n=lane&15], C/D col=lane&15 row=quad*4+reg.

#include <hip/hip_fp16.h>

using f16   = _Float16;
using f16x8 = __attribute__((ext_vector_type(8))) _Float16;
using f32x4 = __attribute__((ext_vector_type(4))) float;

constexpr int NN     = 100000;
constexpr int KK     = 32;
constexpr int LATENT = 64;
constexpr int HIDDEN = 256;
constexpr int OUTD   = 32;

constexpr int NPB   = 64;    // nodes per block
constexpr int BLOCK = 256;   // 4 waves

// ws layout (f16 units): W1f [16 ntile][2 ks][64 lane][8 j]  = 16384 f16
//                        W2f [ 2 ntile][8 ks][64 lane][8 j]  =  8192 f16
constexpr int W2F_OFF = 16384;

__global__ void convert_weights(const float* __restrict__ W1,
                                const float* __restrict__ W2,
                                f16* __restrict__ wsf) {
    const int tid = blockIdx.x * blockDim.x + threadIdx.x;
    if (tid < 16384) {
        const int j = tid & 7, lane = (tid >> 3) & 63, r = tid >> 9; // r=t*2+ks
        const int ks = r & 1, t = r >> 1;
        const int k = ks * 32 + (lane >> 4) * 8 + j;   // latent
        const int n = t * 16 + (lane & 15);            // hidden
        wsf[tid] = (f16)W1[k * HIDDEN + n];
    } else if (tid < 16384 + 8192) {
        const int tid2 = tid - 16384;
        const int j = tid2 & 7, lane = (tid2 >> 3) & 63, r = tid2 >> 9; // r=t*8+ks
        const int ks = r & 7, t = r >> 3;
        const int k = ks * 32 + (lane >> 4) * 8 + j;   // hidden
        const int n = t * 16 + (lane & 15);            // out
        wsf[W2F_OFF + tid2] = (f16)W2[k * OUTD + n];
    }
}

__global__ __launch_bounds__(BLOCK, 3)
void gnn_decoder(const float* __restrict__ z,      // [B, K, LATENT]
                 const float* __restrict__ s,      // [N, K]
                 const int*   __restrict__ batch,  // [N]
                 const f16*   __restrict__ wsf,    // swizzled f16 weights
                 const float* __restrict__ b1,     // [HIDDEN]
                 const float* __restrict__ b2,     // [OUT]
                 float*       __restrict__ out)    // [N, OUT]
{
    __shared__ f16 latf[NPB][LATENT + 8];              // 9216 B, A-frag rows
    __shared__ union U {
        struct P0 {
            float s_tile[NPB][KK + 1];
            int   bidx[NPB];
        } p0;                                          // 8704 B
        f16 hc[NPB][HIDDEN + 8];                       // 33792 B (overlay)
    } u;

    const int t = threadIdx.x;
    const int block_n0 = blockIdx.x * NPB;

    // ---------------- phase 0a: stage s tile + batch indices ----------------
    {
        const float* s_src = s + (size_t)block_n0 * KK;
        #pragma unroll
        for (int idx = t; idx < NPB * KK; idx += BLOCK) {
            const int n = idx >> 5;
            const int gn = block_n0 + n;
            u.p0.s_tile[n][idx & 31] = (gn < NN) ? s_src[idx] : 0.f;
        }
        if (t < NPB) {
            const int gn = block_n0 + t;
            u.p0.bidx[t] = (gn < NN) ? batch[gn] : 0;
        }
    }
    __syncthreads();

    // ------ phase 0b: lat[n][l] = sum_k s[n][k]*z[b][k][l], write f16 -------
    {
        const int n  = t >> 2;
        const int lc = t & 3;
        const int l0 = lc * 16;
        const int b  = u.p0.bidx[n];
        const float* zb = z + (size_t)b * KK * LATENT + l0;

        float acc[16];
        #pragma unroll
        for (int x = 0; x < 16; ++x) acc[x] = 0.f;

        #pragma unroll 4
        for (int k = 0; k < KK; ++k) {
            const float sk = u.p0.s_tile[n][k];
            const float4* zp = (const float4*)(zb + k * LATENT);
            const float4 z0 = zp[0], z1 = zp[1], z2 = zp[2], z3 = zp[3];
            acc[0]  += sk * z0.x;  acc[1]  += sk * z0.y;
            acc[2]  += sk * z0.z;  acc[3]  += sk * z0.w;
            acc[4]  += sk * z1.x;  acc[5]  += sk * z1.y;
            acc[6]  += sk * z1.z;  acc[7]  += sk * z1.w;
            acc[8]  += sk * z2.x;  acc[9]  += sk * z2.y;
            acc[10] += sk * z2.z;  acc[11] += sk * z2.w;
            acc[12] += sk * z3.x;  acc[13] += sk * z3.y;
            acc[14] += sk * z3.z;  acc[15] += sk * z3.w;
        }
        f16x8 p0v, p1v;
        #pragma unroll
        for (int q = 0; q < 8; ++q) { p0v[q] = (f16)acc[q]; p1v[q] = (f16)acc[8 + q]; }
        *(f16x8*)&latf[n][l0]     = p0v;   // ds_write_b128, 16B-aligned
        *(f16x8*)&latf[n][l0 + 8] = p1v;
    }
    __syncthreads();   // latf ready; s_tile dead -> hc overlay safe

    const int lane = t & 63;
    const int w    = __builtin_amdgcn_readfirstlane(t >> 6);  // wave 0..3
    const int lrow = lane & 15;
    const int quad = lane >> 4;

    // ---- stage A: h[64 nodes x 64 hiddens(w)] via MFMA, K=64 ---------------
    f32x4 C[4][4];
    #pragma unroll
    for (int mt = 0; mt < 4; ++mt)
        #pragma unroll
        for (int nt = 0; nt < 4; ++nt)
            C[mt][nt] = (f32x4){0.f, 0.f, 0.f, 0.f};

    const f16x8* W1f = (const f16x8*)wsf;
    #pragma unroll
    for (int ks = 0; ks < 2; ++ks) {
        f16x8 A[4];
        #pragma unroll
        for (int mt = 0; mt < 4; ++mt)
            A[mt] = *(const f16x8*)&latf[mt * 16 + lrow][ks * 32 + quad * 8];
        f16x8 Bv[4];
        #pragma unroll
        for (int nt = 0; nt < 4; ++nt)
            Bv[nt] = W1f[((w * 4 + nt) * 2 + ks) * 64 + lane];  // coalesced 16B
        #pragma unroll
        for (int mt = 0; mt < 4; ++mt)
            #pragma unroll
            for (int nt = 0; nt < 4; ++nt)
                C[mt][nt] = __builtin_amdgcn_mfma_f32_16x16x32_f16(
                                A[mt], Bv[nt], C[mt][nt], 0, 0, 0);
    }

    // relu + b1 -> hc[m][k] f16 (stage-B A-operand layout)
    #pragma unroll
    for (int nt = 0; nt < 4; ++nt) {
        const float b1v = b1[w * 64 + nt * 16 + lrow];
        #pragma unroll
        for (int mt = 0; mt < 4; ++mt) {
            #pragma unroll
            for (int r = 0; r < 4; ++r) {
                float hv = C[mt][nt][r] + b1v;
                hv = hv > 0.f ? hv : 0.f;
                u.hc[mt * 16 + quad * 4 + r][w * 64 + nt * 16 + lrow] = (f16)hv;
            }
        }
    }
    __syncthreads();   // hc fully written

    // ---- stage B: out[w*16..+16, 0..32] via MFMA, K=256 --------------------
    f32x4 O[2];
    O[0] = (f32x4){0.f, 0.f, 0.f, 0.f};
    O[1] = (f32x4){0.f, 0.f, 0.f, 0.f};

    const f16x8* W2f = (const f16x8*)(wsf + W2F_OFF);
    #pragma unroll
    for (int ks = 0; ks < 8; ++ks) {
        const f16x8 Ah = *(const f16x8*)&u.hc[w * 16 + lrow][ks * 32 + quad * 8];
        #pragma unroll
        for (int nt = 0; nt < 2; ++nt) {
            const f16x8 Bv = W2f[(nt * 8 + ks) * 64 + lane];
            O[nt] = __builtin_amdgcn_mfma_f32_16x16x32_f16(Ah, Bv, O[nt], 0, 0, 0);
        }
    }

    // ---- epilogue: + b2, store (4 quads x 64B sectors per instr) -----------
    #pragma unroll
    for (int nt = 0; nt < 2; ++nt) {
        const float b2v = b2[nt * 16 + lrow];
        #pragma unroll
        for (int r = 0; r < 4; ++r) {
            const int m  = w * 16 + quad * 4 + r;
            const int gn = block_n0 + m;
            if (gn < NN)
                out[(size_t)gn * OUTD + nt * 16 + lrow] = O[nt][r] + b2v;
        }
    }
}

extern "C" void kernel_launch(void* const* d_in, const int* in_sizes, int n_in,
                              void* d_out, int out_size, void* d_ws, size_t ws_size,
                              hipStream_t stream) {
    const float* z     = (const float*)d_in[0];
    const float* s     = (const float*)d_in[1];
    const int*   batch = (const int*)d_in[2];
    const float* W1    = (const float*)d_in[3];
    const float* b1    = (const float*)d_in[4];
    const float* W2    = (const float*)d_in[5];
    const float* b2    = (const float*)d_in[6];
    float* out = (float*)d_out;
    f16* wsf = (f16*)d_ws;   // needs 48 KB

    convert_weights<<<96, 256, 0, stream>>>(W1, W2, wsf);

    const int grid = (NN + NPB - 1) / NPB;  // 1563
    gnn_decoder<<<grid, BLOCK, 0, stream>>>(z, s, batch, wsf, b1, b2, out);
}